// Round 23
// baseline (246.385 us; speedup 1.0000x reference)
//
#include <hip/hip_runtime.h>
#include <hip/hip_bf16.h>

#define BATCH 4
#define CIN 64
#define HH 352
#define WW 1216
#define OCH 8
#define OHH 354
#define OWW 1218
#define HW (HH * WW)

#define BH 16            // output rows per block
#define BW 64            // output cols per block
#define FR 18            // staged rows (halo)
#define FC 66            // staged cols (halo)
#define NPOS (FR * FC)   // 1188
#define NTHR 512         // 8 waves: 4 h-groups x 2 w-groups
#define NIT 5            // staging tasks per thread per chunk
#define GX 19            // WW/BW
#define GY 22            // HH/BH
#define NWG (GX * GY * BATCH)   // 1672 = 8 * 209
#define CPX (NWG / 8)           // 209 blocks per XCD

typedef short bf16x4 __attribute__((ext_vector_type(4)));
typedef float f32x4  __attribute__((ext_vector_type(4)));

// Select the MFMA builtin ONLY in the device pass; host pass gets an inert
// stub (host parses kernel bodies but never runs them). r22's #error fired
// in the HOST compile where no amdgcn builtins exist.
#if defined(__HIP_DEVICE_COMPILE__)
#if __has_builtin(__builtin_amdgcn_mfma_f32_16x16x16bf16_1k)
#define MFMA16(A, B, C) __builtin_amdgcn_mfma_f32_16x16x16bf16_1k(A, B, C, 0, 0, 0)
#elif __has_builtin(__builtin_amdgcn_mfma_f32_16x16x16_bf16)
#define MFMA16(A, B, C) __builtin_amdgcn_mfma_f32_16x16x16_bf16(A, B, C, 0, 0, 0)
#else
#error "no 16x16x16 bf16 mfma builtin on device"
#endif
#else
#define MFMA16(A, B, C) (C)   // host stub, never executed
#endif

// fp32 -> bf16 round-to-nearest-even (branchless, finite inputs)
static __device__ __forceinline__ unsigned f2bf(float x) {
    unsigned u = __float_as_uint(x);
    return (u + 0x7FFFu + ((u >> 16) & 1u)) >> 16;
}

// Bake weights into K=16 MFMA B-fragment layout (bf16, BN-folded, oc>=8 zero):
// wB[(tap*4+q)*64 + lane] = 4 bf16: k = hi*4+j -> ch = q*16 + hi*4 + j, col = oc
__global__ void repack_kernel(const float* __restrict__ conv_w,
                              const float* __restrict__ gamma,
                              const float* __restrict__ beta,
                              const float* __restrict__ mean,
                              const float* __restrict__ var,
                              unsigned short* __restrict__ wB,
                              float* __restrict__ bias)
{
    int tid = blockIdx.x * 256 + threadIdx.x;
    if (tid < 36 * 64) {
        int tc = tid >> 6;          // tap*4 + q
        int lane = tid & 63;
        int tap = tc >> 2, q = tc & 3;
        int oc = lane & 15, hi = lane >> 4;
        unsigned v[4];
#pragma unroll
        for (int j = 0; j < 4; ++j) {
            float w = 0.f;
            if (oc < 8) {
                int c = q * 16 + hi * 4 + j;
                float scl = gamma[oc] * rsqrtf(var[oc] + 1e-5f);
                w = conv_w[((size_t)oc * CIN + c) * 9 + tap] * scl;
            }
            v[j] = f2bf(w);
        }
        uint2 pk;
        pk.x = v[0] | (v[1] << 16);
        pk.y = v[2] | (v[3] << 16);
        ((uint2*)wB)[tid] = pk;
    }
    if (tid < OCH) {
        float scl = gamma[tid] * rsqrtf(var[tid] + 1e-5f);
        bias[tid] = beta[tid] - mean[tid] * scl;
    }
}

// Zero only the uncovered border ring of each (b,t) OUTPUT plane.
__global__ void border_kernel(float* __restrict__ out)
{
    const int bt = blockIdx.x;          // 0..35
    const int t = bt % 9;
    const int i = t / 3, j = t % 3;
    float* pl = out + (size_t)bt * OHH * OWW;
    const int r0 = (i == 0) ? HH : 0;
    const int r1 = (i == 2) ? 1 : (OHH - 1);
    const int c0 = (j == 0) ? WW : 0;
    const int c1 = (j == 2) ? 1 : (OWW - 1);
    const int nrow = 2 * OWW;
    for (int idx = threadIdx.x; idx < 2 * OWW + 2 * OHH; idx += blockDim.x) {
        if (idx < nrow) {
            int r = (idx < OWW) ? r0 : r1;
            int c = (idx < OWW) ? idx : idx - OWW;
            pl[(size_t)r * OWW + c] = 0.f;
        } else {
            int k = idx - nrow;
            int c = (k < OHH) ? c0 : c1;
            int r = (k < OHH) ? k : k - OHH;
            pl[(size_t)r * OWW + c] = 0.f;
        }
    }
}

__global__ __launch_bounds__(NTHR, 2)
void conv_mfma(const float* __restrict__ feature,
               const unsigned short* __restrict__ wB,
               const float* __restrict__ bias,
               float* __restrict__ out)
{
    // [pos][oct]: 16 ch per pos = 32 B. Linear layout; a wave's A-read of
    // 16 consecutive pos x 4 hi covers a contiguous 512B span -> conflict-free.
    __shared__ uint4 sF[NPOS * 2];   // 38016 B

    // Bijective XCD swizzle (1672 = 8*209).
    const int lin = blockIdx.x;
    const int wg  = (lin & 7) * CPX + (lin >> 3);
    const int bx  = wg % GX;
    const int byz = wg / GX;
    const int by  = byz % GY;
    const int b   = byz / GY;

    const int tid  = threadIdx.x;
    const int wave = tid >> 6;          // 0..7
    const int lane = tid & 63;
    const int oc   = lane & 15;
    const int hi   = lane >> 4;
    const int hb   = (wave >> 1) * 4;   // wave h-base (4 rows)
    const int wb   = (wave & 1) * 32;   // wave w-base (32 cols)
    const int h0 = by * BH;
    const int w0 = bx * BW;

    const float* fb = feature + (size_t)b * CIN * HW;
    const int soct = tid & 1;           // ch octet within 16-ch chunk
    const int p0   = tid >> 1;          // 0..255

    // Chunk-invariant staging geometry (held in ~15 regs).
    int   off[NIT], sl[NIT];
    float mk[NIT];
#pragma unroll
    for (int it = 0; it < NIT; ++it) {
        int pos = p0 + it * 256;
        pos = (pos < NPOS) ? pos : (NPOS - 1);   // tail: benign duplicate
        int fr = pos / FC;
        int fc = pos - fr * FC;
        int gh = h0 - 1 + fr, gw = w0 - 1 + fc;
        mk[it] = (((unsigned)gh < (unsigned)HH) && ((unsigned)gw < (unsigned)WW)) ? 1.f : 0.f;
        off[it] = min(max(gh, 0), HH - 1) * WW + min(max(gw, 0), WW - 1);
        sl[it]  = pos * 2 + soct;
    }

    f32x4 acc[4][2];
#pragma unroll
    for (int rr = 0; rr < 4; ++rr)
#pragma unroll
        for (int cg = 0; cg < 2; ++cg) acc[rr][cg] = (f32x4)0.f;

#pragma unroll 1
    for (int q = 0; q < 4; ++q) {       // 16-ch chunks
        if (q) __syncthreads();
        const float* chbase = fb + (size_t)(q * 16 + soct * 8) * HW;

        float v[NIT][8];
#pragma unroll
        for (int it = 0; it < NIT; ++it) {
            const float* sp = chbase + off[it];
#pragma unroll
            for (int j = 0; j < 8; ++j) v[it][j] = sp[(size_t)j * HW];
        }
#pragma unroll
        for (int it = 0; it < NIT; ++it) {
            float m_ = mk[it];
            uint4 pk;
            pk.x = f2bf(v[it][0] * m_) | (f2bf(v[it][1] * m_) << 16);
            pk.y = f2bf(v[it][2] * m_) | (f2bf(v[it][3] * m_) << 16);
            pk.z = f2bf(v[it][4] * m_) | (f2bf(v[it][5] * m_) << 16);
            pk.w = f2bf(v[it][6] * m_) | (f2bf(v[it][7] * m_) << 16);
            sF[sl[it]] = pk;
        }
        __syncthreads();

        bf16x4 bwl[9];
#pragma unroll
        for (int t = 0; t < 9; ++t)
            bwl[t] = ((const bf16x4*)wB)[(t * 4 + q) * 64 + lane];

#pragma unroll
        for (int t = 0; t < 9; ++t) {
            const int dh = t / 3, dw = t % 3;
#pragma unroll
            for (int rr = 0; rr < 4; ++rr) {
                const int fr = hb + rr + dh;
#pragma unroll
                for (int cg = 0; cg < 2; ++cg) {
                    const int fc = wb + cg * 16 + oc + dw;
                    const int pp = fr * FC + fc;
                    bf16x4 av = *reinterpret_cast<const bf16x4*>(
                        (const short*)sF + pp * 16 + hi * 4);
                    acc[rr][cg] = MFMA16(av, bwl[t], acc[rr][cg]);
                }
            }
        }
    }

    // ---- epilogue: bias, L1-normalize across oc (16-lane shfl), mid, scatter ----
    const float myb = (oc < 8) ? bias[oc] : 0.f;
    const int t = (oc < 8) ? ((oc < 4) ? oc : oc + 1) : 4;
    const bool dow = (oc <= 8);
    const int ii = t / 3, jj = t % 3;
    float* pl = out + ((size_t)(b * 9 + t) * OHH + ii) * OWW + jj;

#pragma unroll
    for (int rr = 0; rr < 4; ++rr) {
        const int h = h0 + hb + rr;
#pragma unroll
        for (int cg = 0; cg < 2; ++cg) {
#pragma unroll
            for (int reg = 0; reg < 4; ++reg) {
                float vv = acc[rr][cg][reg] + myb;   // lanes oc>=8: 0
                float av = fabsf(vv);
                float sv = vv;
                av += __shfl_xor(av, 1);  sv += __shfl_xor(sv, 1);
                av += __shfl_xor(av, 2);  sv += __shfl_xor(sv, 2);
                av += __shfl_xor(av, 4);  sv += __shfl_xor(sv, 4);
                av += __shfl_xor(av, 8);  sv += __shfl_xor(sv, 8);
                float inv = 1.0f / av;
                float val = (oc == 8) ? (1.0f - sv * inv) : (vv * inv);
                if (dow) {
                    int w = w0 + wb + cg * 16 + hi * 4 + reg;
                    pl[(size_t)h * OWW + w] = val;
                }
            }
        }
    }
}

extern "C" void kernel_launch(void* const* d_in, const int* in_sizes, int n_in,
                              void* d_out, int out_size, void* d_ws, size_t ws_size,
                              hipStream_t stream) {
    const float* feature = (const float*)d_in[0];
    const float* conv_w  = (const float*)d_in[1];
    const float* gamma   = (const float*)d_in[2];
    const float* beta    = (const float*)d_in[3];
    const float* mean    = (const float*)d_in[4];
    const float* var     = (const float*)d_in[5];
    float* out = (float*)d_out;

    unsigned short* wB = (unsigned short*)d_ws;    // 18432 B
    float* bias = (float*)((char*)d_ws + 18432);   // 32 B

    border_kernel<<<BATCH * 9, 256, 0, stream>>>(out);
    repack_kernel<<<9, 256, 0, stream>>>(conv_w, gamma, beta, mean, var, wB, bias);
    conv_mfma<<<NWG, NTHR, 0, stream>>>(feature, wB, bias, out);
}